// Round 1
// baseline (425.869 us; speedup 1.0000x reference)
//
#include <hip/hip_runtime.h>
#include <math.h>

#define NFFT 8192
#define KMAX 32
#define BB   32
#define CC   64
#define HH   10
#define KD   (KMAX*CC*CC)   // 131072

// ---- workspace float offsets ----
#define OFF_T   0
#define SZ_T    (NFFT*KMAX*2)          // 524288 (2 MiB twiddle table: cos,sin of +2pi*k*n/N)
#define OFF_H   (OFF_T + SZ_T)
#define SZ_H    768                     // 320 h_r + 320 h_c
#define OFF_X   (OFF_H + SZ_H)
#define SZ_X    (BB*KMAX*CC*2)          // 131072  X[b][k][c][2]
#define OFF_Y   (OFF_X + SZ_X)
#define SZ_Y    (BB*CC*KMAX*2)          // 131072  Y[b][o][k][2]
#define OFF_P   (OFF_Y + SZ_Y)
#define NCH     32
#define CHUNK   (NFFT/NCH)              // 256
#define SZ_P    (BB*NCH*CC*KMAX*2)      // 4194304 P[b][ch][c][kf]
#define OFF_K   (OFF_P + SZ_P)
#define SZ_K    (BB*KD*2)               // 8388608 Kc[b][k][i][o][2]

// twiddle table: T[n][k] = (cos, sin) of 2*pi*(n*k mod N)/N
__global__ __launch_bounds__(256) void k_twiddle(float* __restrict__ T) {
    int id = blockIdx.x * 256 + threadIdx.x;      // 0 .. N*KMAX-1
    int n = id >> 5, k = id & 31;
    int t = (n * k) & (NFFT - 1);                 // exact integer phase
    float s, c;
    sincospif(2.0f * (float)t / (float)NFFT, &s, &c);
    ((float2*)T)[id] = make_float2(c, s);
}

// h[b][j] = swish(p[b]*W1[j] + b1[j]) for r and c MLPs (320 values each)
__global__ void k_h(const float* __restrict__ p,
                    const float* __restrict__ W1r, const float* __restrict__ b1r,
                    const float* __restrict__ W1c, const float* __restrict__ b1c,
                    float* __restrict__ Hws) {
    int t = threadIdx.x;
    if (t < BB * HH) {
        int b = t / HH, j = t % HH;
        float xr = p[b] * W1r[j] + b1r[j];
        float xc = p[b] * W1c[j] + b1c[j];
        Hws[t]            = xr / (1.0f + expf(-xr));
        Hws[BB * HH + t]  = xc / (1.0f + expf(-xc));
    }
}

// Stage A: truncated DFT partials. Block = (chunk ch, batch b), 256 thr.
// thread: c = tid&63, kg = tid>>6 owns 8 complex modes. Loops 256 n.
__global__ __launch_bounds__(256) void k_dft(const float* __restrict__ f,
                                             const float* __restrict__ T,
                                             float* __restrict__ P) {
    int ch = blockIdx.x, b = blockIdx.y;
    int c  = threadIdx.x & 63;
    int kg = threadIdx.x >> 6;
    float accR[8], accI[8];
#pragma unroll
    for (int q = 0; q < 8; ++q) { accR[q] = 0.f; accI[q] = 0.f; }
    const float*  fp = f + ((size_t)(b * NFFT + ch * CHUNK)) * CC + c;
    const float4* Tp = (const float4*)(T + (size_t)(ch * CHUNK) * (KMAX * 2) + kg * 16);
#pragma unroll 4
    for (int n = 0; n < CHUNK; ++n) {
        float fv = fp[(size_t)n * CC];                 // coalesced: lane = c
        float4 t0 = Tp[n * 16 + 0];                    // wave-uniform broadcasts
        float4 t1 = Tp[n * 16 + 1];
        float4 t2 = Tp[n * 16 + 2];
        float4 t3 = Tp[n * 16 + 3];
        accR[0] = fmaf(fv, t0.x, accR[0]); accI[0] = fmaf(-fv, t0.y, accI[0]);
        accR[1] = fmaf(fv, t0.z, accR[1]); accI[1] = fmaf(-fv, t0.w, accI[1]);
        accR[2] = fmaf(fv, t1.x, accR[2]); accI[2] = fmaf(-fv, t1.y, accI[2]);
        accR[3] = fmaf(fv, t1.z, accR[3]); accI[3] = fmaf(-fv, t1.w, accI[3]);
        accR[4] = fmaf(fv, t2.x, accR[4]); accI[4] = fmaf(-fv, t2.y, accI[4]);
        accR[5] = fmaf(fv, t2.z, accR[5]); accI[5] = fmaf(-fv, t2.w, accI[5]);
        accR[6] = fmaf(fv, t3.x, accR[6]); accI[6] = fmaf(-fv, t3.y, accI[6]);
        accR[7] = fmaf(fv, t3.z, accR[7]); accI[7] = fmaf(-fv, t3.w, accI[7]);
    }
    float4* Pp = (float4*)(P + (((size_t)(b * NCH + ch) * CC + c) * (KMAX * 2)) + kg * 16);
    Pp[0] = make_float4(accR[0], accI[0], accR[1], accI[1]);
    Pp[1] = make_float4(accR[2], accI[2], accR[3], accI[3]);
    Pp[2] = make_float4(accR[4], accI[4], accR[5], accI[5]);
    Pp[3] = make_float4(accR[6], accI[6], accR[7], accI[7]);
}

// reduce partials over chunks; transpose-write X[b][k][c][2]
__global__ __launch_bounds__(256) void k_reduce(const float* __restrict__ P,
                                                float* __restrict__ X) {
    int w = threadIdx.x >> 6, lane = threadIdx.x & 63;  // lane = kf
    int r = blockIdx.x * 4 + w;                          // r = b*64 + c
    int b = r >> 6, c = r & 63;
    const float* Pp = P + ((size_t)(b * NCH) * CC + c) * (KMAX * 2) + lane;
    float acc = 0.f;
#pragma unroll 4
    for (int ch = 0; ch < NCH; ++ch)
        acc += Pp[(size_t)ch * CC * KMAX * 2];          // coalesced reads
    int k = lane >> 1, ri = lane & 1;
    X[(((size_t)b * KMAX + k) * CC + c) * 2 + ri] = acc; // scattered tiny write
}

// Stage B: build complex kernel Kc[b][k][i][o][2]; W2 read ONCE for all 32 b.
__global__ __launch_bounds__(256) void k_kb(const float* __restrict__ W2r, const float* __restrict__ b2r,
                                            const float* __restrict__ W2c, const float* __restrict__ b2c,
                                            const float* __restrict__ Hws, float* __restrict__ Kc) {
    __shared__ float h[640];
    int tid = threadIdx.x;
    h[tid] = Hws[tid];
    h[256 + tid] = Hws[256 + tid];
    if (tid < 128) h[512 + tid] = Hws[512 + tid];
    __syncthreads();
    int idx = blockIdx.x * 256 + tid;                    // 0..KD-1
    float wr[HH], wc[HH];
#pragma unroll
    for (int j = 0; j < HH; ++j) {
        wr[j] = W2r[(size_t)j * KD + idx];
        wc[j] = W2c[(size_t)j * KD + idx];
    }
    float br = b2r[idx], bc = b2c[idx];
    float2* outp = (float2*)Kc + idx;
    for (int b = 0; b < BB; ++b) {
        float rk = br, ck = bc;
#pragma unroll
        for (int j = 0; j < HH; ++j) {
            rk = fmaf(h[b * HH + j],       wr[j], rk);
            ck = fmaf(h[320 + b * HH + j], wc[j], ck);
        }
        outp[(size_t)b * KD] = make_float2(rk, ck);
    }
}

// Stage C: y[b,o,k] = sum_i Kc[b,k,i,o] * X[b,i,k]  (complex), scaled by 1/N
__global__ __launch_bounds__(256) void k_mix(const float* __restrict__ Kc,
                                             const float* __restrict__ X,
                                             float* __restrict__ Y) {
    int k = blockIdx.x, b = blockIdx.y;
    int o = threadIdx.x & 63, ig = threadIdx.x >> 6;
    __shared__ float xs[128];
    __shared__ float red[4][64][2];
    if (threadIdx.x < 32)
        ((float4*)xs)[threadIdx.x] =
            ((const float4*)(X + ((size_t)(b * KMAX + k) * CC) * 2))[threadIdx.x];
    __syncthreads();
    const float2* Kp = (const float2*)Kc + (size_t)b * KD + k * CC * CC + o;
    float yr = 0.f, yi = 0.f;
#pragma unroll 4
    for (int t = 0; t < 16; ++t) {
        int i = ig * 16 + t;
        float2 rc = Kp[(size_t)i * CC];                 // coalesced over o
        float xr = xs[2 * i], xi = xs[2 * i + 1];
        yr = fmaf(rc.x, xr, yr); yr = fmaf(-rc.y, xi, yr);
        yi = fmaf(rc.x, xi, yi); yi = fmaf(rc.y, xr, yi);
    }
    red[ig][o][0] = yr; red[ig][o][1] = yi;
    __syncthreads();
    if (threadIdx.x < 64) {
        float sr = red[0][o][0] + red[1][o][0] + red[2][o][0] + red[3][o][0];
        float si = red[0][o][1] + red[1][o][1] + red[2][o][1] + red[3][o][1];
        const float sc = 1.0f / (float)NFFT;
        ((float2*)Y)[((size_t)b * CC + o) * KMAX + k] = make_float2(sr * sc, si * sc);
    }
}

// Stage D: out[b,n,c] = sum_k ( yr*cos + (-yi)*sin ), y in registers
__global__ __launch_bounds__(256) void k_idft(const float* __restrict__ Y,
                                              const float* __restrict__ T,
                                              float* __restrict__ out) {
    int ch = blockIdx.x, b = blockIdx.y;
    int c = threadIdx.x & 63, w = threadIdx.x >> 6;
    float yv[64];
    const float4* Yp = (const float4*)(Y + (size_t)(b * CC + c) * (KMAX * 2));
#pragma unroll
    for (int q = 0; q < 16; ++q) {
        float4 v = Yp[q];
        yv[4 * q] = v.x; yv[4 * q + 1] = v.y; yv[4 * q + 2] = v.z; yv[4 * q + 3] = v.w;
    }
    int n0 = ch * 128 + w * 32;                          // each wave: own 32-n strip
    const float4* Tp = (const float4*)(T + (size_t)n0 * (KMAX * 2));
    float* op = out + ((size_t)b * NFFT + n0) * CC + c;
#pragma unroll 2
    for (int nl = 0; nl < 32; ++nl) {
        float acc = 0.f;
#pragma unroll
        for (int q = 0; q < 16; ++q) {
            float4 t = Tp[nl * 16 + q];                  // wave-uniform broadcast
            acc = fmaf(yv[4 * q],      t.x, acc);
            acc = fmaf(-yv[4 * q + 1], t.y, acc);
            acc = fmaf(yv[4 * q + 2],  t.z, acc);
            acc = fmaf(-yv[4 * q + 3], t.w, acc);
        }
        op[(size_t)nl * CC] = acc;                       // coalesced: lane = c
    }
}

extern "C" void kernel_launch(void* const* d_in, const int* in_sizes, int n_in,
                              void* d_out, int out_size, void* d_ws, size_t ws_size,
                              hipStream_t stream) {
    const float* f   = (const float*)d_in[0];
    const float* p   = (const float*)d_in[1];
    const float* W1r = (const float*)d_in[2];
    const float* b1r = (const float*)d_in[3];
    const float* W2r = (const float*)d_in[4];
    const float* b2r = (const float*)d_in[5];
    const float* W1c = (const float*)d_in[6];
    const float* b1c = (const float*)d_in[7];
    const float* W2c = (const float*)d_in[8];
    const float* b2c = (const float*)d_in[9];
    float* ws  = (float*)d_ws;
    float* T   = ws + OFF_T;
    float* Hp  = ws + OFF_H;
    float* X   = ws + OFF_X;
    float* Yw  = ws + OFF_Y;
    float* P   = ws + OFF_P;
    float* Kc  = ws + OFF_K;
    float* o   = (float*)d_out;

    k_twiddle<<<(NFFT * KMAX) / 256, 256, 0, stream>>>(T);
    k_h      <<<1, 320, 0, stream>>>(p, W1r, b1r, W1c, b1c, Hp);
    k_dft    <<<dim3(NCH, BB), 256, 0, stream>>>(f, T, P);
    k_reduce <<<(BB * CC) / 4, 256, 0, stream>>>(P, X);
    k_kb     <<<KD / 256, 256, 0, stream>>>(W2r, b2r, W2c, b2c, Hp, Kc);
    k_mix    <<<dim3(KMAX, BB), 256, 0, stream>>>(Kc, X, Yw);
    k_idft   <<<dim3(NFFT / 128, BB), 256, 0, stream>>>(Yw, T, o);
}

// Round 4
// 242.560 us; speedup vs baseline: 1.7557x; 1.7557x over previous
//
#include <hip/hip_runtime.h>
#include <math.h>

#define NFFT 8192
#define KMAX 32
#define BB   32
#define CC   64
#define HH   10
#define KD   (KMAX*CC*CC)   // 131072

// ---- workspace float offsets ----
#define OFF_T   0
#define SZ_T    (NFFT*KMAX*2)           // 524288 (2 MiB twiddle: cos,sin of +2pi*n*k/N)
#define OFF_H   (OFF_T + SZ_T)
#define SZ_H    768
#define OFF_X   (OFF_H + SZ_H)
#define SZ_X    (BB*KMAX*CC*2)          // 131072  X[b][j][c][2]
#define OFF_Y   (OFF_X + SZ_X)
#define SZ_Y    (BB*CC*KMAX*2)          // 131072  Y[b][o][k][2]
#define NCH     64
#define CHUNK   (NFFT/NCH)              // 128
// P[ch][b][comp][c] (33.5 MB) aliases Kc[b][k][i][o][2] (33.5 MB):
// P is dead after k_reduce2; Kc is written by k_kb afterwards (stream-ordered).
#define OFF_P   (OFF_Y + SZ_Y)
#define SZ_P    (NCH*BB*64*CC)          // 8388608
#define OFF_K   OFF_P

// twiddle table: T[n][2j]=cos(2pi*n*j/N), T[n][2j+1]=sin(2pi*n*j/N)
__global__ __launch_bounds__(256) void k_twiddle(float* __restrict__ T) {
    int id = blockIdx.x * 256 + threadIdx.x;      // 0 .. N*KMAX-1
    int n = id >> 5, k = id & 31;
    int t = (n * k) & (NFFT - 1);                 // exact integer phase
    float s, c;
    sincospif(2.0f * (float)t / (float)NFFT, &s, &c);
    ((float2*)T)[id] = make_float2(c, s);
}

__global__ void k_h(const float* __restrict__ p,
                    const float* __restrict__ W1r, const float* __restrict__ b1r,
                    const float* __restrict__ W1c, const float* __restrict__ b1c,
                    float* __restrict__ Hws) {
    int t = threadIdx.x;
    if (t < BB * HH) {
        int b = t / HH, j = t % HH;
        float xr = p[b] * W1r[j] + b1r[j];
        float xc = p[b] * W1c[j] + b1c[j];
        Hws[t]            = xr / (1.0f + expf(-xr));
        Hws[BB * HH + t]  = xc / (1.0f + expf(-xc));
    }
}

// Stage A: truncated DFT. Block=(ch, bg): 8 b, 128 n. Wave w owns modes w*4..w*4+3.
// 64 acc/thread -> 64 FMA per 8 f-loads + 2 LDS broadcasts per n.
__global__ __launch_bounds__(512, 2) void k_dft2(const float* __restrict__ f,
                                                 const float* __restrict__ T,
                                                 float* __restrict__ P) {
    __shared__ float Ts[CHUNK * 64];              // 32 KB T strip
    const int ch = blockIdx.x;
    const int b0 = blockIdx.y * 8;
    const int t  = threadIdx.x;
    {   // stage T strip: 8192 floats, coalesced float4
        const float4* src = (const float4*)(T + (size_t)ch * CHUNK * 64);
        float4* dst = (float4*)Ts;
#pragma unroll
        for (int q = 0; q < 4; ++q) dst[t + q * 512] = src[t + q * 512];
    }
    __syncthreads();
    const int c = t & 63;
    const int w = t >> 6;                         // wave id: modes j0 = w*4
    float accR[8][4], accI[8][4];
#pragma unroll
    for (int bi = 0; bi < 8; ++bi)
#pragma unroll
        for (int m = 0; m < 4; ++m) { accR[bi][m] = 0.f; accI[bi][m] = 0.f; }
    const float* fp = f + ((size_t)b0 * NFFT + ch * CHUNK) * CC + c;
#pragma unroll 2
    for (int n = 0; n < CHUNK; ++n) {
        float fv[8];
#pragma unroll
        for (int bi = 0; bi < 8; ++bi)
            fv[bi] = fp[(size_t)bi * NFFT * CC + n * CC];   // coalesced, L1-shared
        float4 t0 = *(const float4*)(Ts + n * 64 + w * 8);   // uniform broadcast
        float4 t1 = *(const float4*)(Ts + n * 64 + w * 8 + 4);
#pragma unroll
        for (int bi = 0; bi < 8; ++bi) {
            accR[bi][0] = fmaf(fv[bi],  t0.x, accR[bi][0]);
            accI[bi][0] = fmaf(-fv[bi], t0.y, accI[bi][0]);
            accR[bi][1] = fmaf(fv[bi],  t0.z, accR[bi][1]);
            accI[bi][1] = fmaf(-fv[bi], t0.w, accI[bi][1]);
            accR[bi][2] = fmaf(fv[bi],  t1.x, accR[bi][2]);
            accI[bi][2] = fmaf(-fv[bi], t1.y, accI[bi][2]);
            accR[bi][3] = fmaf(fv[bi],  t1.z, accR[bi][3]);
            accI[bi][3] = fmaf(-fv[bi], t1.w, accI[bi][3]);
        }
    }
    // P[ch][b][comp][c], comp = w*8 + 2m (+1 for imag) -- coalesced dword stores
#pragma unroll
    for (int bi = 0; bi < 8; ++bi) {
        float* Pp = P + (((size_t)ch * BB + b0 + bi) * 64 + w * 8) * CC + c;
#pragma unroll
        for (int m = 0; m < 4; ++m) {
            Pp[(2 * m) * CC]     = accR[bi][m];
            Pp[(2 * m + 1) * CC] = accI[bi][m];
        }
    }
}

// reduce partials over 64 chunks -> X[b][j][c][2]
__global__ __launch_bounds__(256) void k_reduce2(const float* __restrict__ P,
                                                 float* __restrict__ X) {
    int t = threadIdx.x;
    int c = t & 63, d = t >> 6;
    int b = blockIdx.x, cg = blockIdx.y;          // cg 0..15
    int comp = cg * 4 + d;
    const float* Pp = P + ((size_t)b * 64 + comp) * CC + c;
    float acc = 0.f;
#pragma unroll 8
    for (int ch = 0; ch < NCH; ++ch)
        acc += Pp[(size_t)ch * BB * 64 * CC];     // coalesced
    int j = comp >> 1, ri = comp & 1;
    X[(((size_t)b * KMAX + j) * CC + c) * 2 + ri] = acc;
}

// Stage B: complex kernel Kc[b][k][i][o][2]; W2 read once for all 32 b.
__global__ __launch_bounds__(256) void k_kb(const float* __restrict__ W2r, const float* __restrict__ b2r,
                                            const float* __restrict__ W2c, const float* __restrict__ b2c,
                                            const float* __restrict__ Hws, float* __restrict__ Kc) {
    __shared__ float h[640];
    int tid = threadIdx.x;
    h[tid] = Hws[tid];
    h[256 + tid] = Hws[256 + tid];
    if (tid < 128) h[512 + tid] = Hws[512 + tid];
    __syncthreads();
    int idx = blockIdx.x * 256 + tid;
    float wr[HH], wc[HH];
#pragma unroll
    for (int j = 0; j < HH; ++j) {
        wr[j] = W2r[(size_t)j * KD + idx];
        wc[j] = W2c[(size_t)j * KD + idx];
    }
    float br = b2r[idx], bc = b2c[idx];
    float2* outp = (float2*)Kc + idx;
    for (int b = 0; b < BB; ++b) {
        float rk = br, ck = bc;
#pragma unroll
        for (int j = 0; j < HH; ++j) {
            rk = fmaf(h[b * HH + j],       wr[j], rk);
            ck = fmaf(h[320 + b * HH + j], wc[j], ck);
        }
        outp[(size_t)b * KD] = make_float2(rk, ck);
    }
}

// Stage C: y[b,o,k] = sum_i Kc[b,k,i,o] * X[b,i,k] (complex), scaled 1/N
__global__ __launch_bounds__(256) void k_mix(const float* __restrict__ Kc,
                                             const float* __restrict__ X,
                                             float* __restrict__ Y) {
    int k = blockIdx.x, b = blockIdx.y;
    int o = threadIdx.x & 63, ig = threadIdx.x >> 6;
    __shared__ float xs[128];
    __shared__ float red[4][64][2];
    if (threadIdx.x < 32)
        ((float4*)xs)[threadIdx.x] =
            ((const float4*)(X + ((size_t)(b * KMAX + k) * CC) * 2))[threadIdx.x];
    __syncthreads();
    const float2* Kp = (const float2*)Kc + (size_t)b * KD + k * CC * CC + o;
    float yr = 0.f, yi = 0.f;
#pragma unroll 4
    for (int t = 0; t < 16; ++t) {
        int i = ig * 16 + t;
        float2 rc = Kp[(size_t)i * CC];
        float xr = xs[2 * i], xi = xs[2 * i + 1];
        yr = fmaf(rc.x, xr, yr); yr = fmaf(-rc.y, xi, yr);
        yi = fmaf(rc.x, xi, yi); yi = fmaf(rc.y, xr, yi);
    }
    red[ig][o][0] = yr; red[ig][o][1] = yi;
    __syncthreads();
    if (threadIdx.x < 64) {
        float sr = red[0][o][0] + red[1][o][0] + red[2][o][0] + red[3][o][0];
        float si = red[0][o][1] + red[1][o][1] + red[2][o][1] + red[3][o][1];
        const float sc = 1.0f / (float)NFFT;
        ((float2*)Y)[((size_t)b * CC + o) * KMAX + k] = make_float2(sr * sc, si * sc);
    }
}

// Stage D: iDFT as GEMM  out[row=(b,c)][n] = sum_k zt[k][row]*tt[k][n]
// zt[2j]=yr, zt[2j+1]=-yi ; tt[2j]=cos, tt[2j+1]=sin. M256 x N256 tile, K=64.
__global__ __launch_bounds__(512, 2) void k_idft2(const float* __restrict__ Y,
                                                  const float* __restrict__ T,
                                                  float* __restrict__ out) {
    extern __shared__ float lds[];                // zt[64][256] | tt[64][256] = 128 KB
    float* zt = lds;
    float* tt = lds + 64 * 256;
    const int t  = threadIdx.x;
    const int n0 = blockIdx.x * 256;
    const int b0 = blockIdx.y * 4;
    {   // stage zt (sign-folded) and tt, transposed
        int row = t >> 1, kh = t & 1;             // row = b_l*64 + c ; also reused as nl
        const float4* src = (const float4*)(Y + ((size_t)(b0 + (row >> 6)) * CC + (row & 63)) * (KMAX * 2) + kh * 32);
        const float4* ts  = (const float4*)(T + (size_t)(n0 + row) * (KMAX * 2) + kh * 32);
#pragma unroll
        for (int q = 0; q < 8; ++q) {
            float4 v = src[q];
            int k = kh * 32 + q * 4;
            zt[(k + 0) * 256 + row] =  v.x;
            zt[(k + 1) * 256 + row] = -v.y;       // -yi
            zt[(k + 2) * 256 + row] =  v.z;
            zt[(k + 3) * 256 + row] = -v.w;
            float4 u = ts[q];
            tt[(k + 0) * 256 + row] = u.x;
            tt[(k + 1) * 256 + row] = u.y;
            tt[(k + 2) * 256 + row] = u.z;
            tt[(k + 3) * 256 + row] = u.w;
        }
    }
    __syncthreads();
    const int rg = t & 15;                        // rows rg*4 + 64*i (strided -> conflict-free b128)
    const int ng = t >> 4;                        // n cols ng*8..ng*8+7
    float acc[4][4][8];
#pragma unroll
    for (int i = 0; i < 4; ++i)
#pragma unroll
        for (int j = 0; j < 4; ++j)
#pragma unroll
            for (int n = 0; n < 8; ++n) acc[i][j][n] = 0.f;
#pragma unroll 2
    for (int k = 0; k < 64; ++k) {
        float4 z[4];
#pragma unroll
        for (int i = 0; i < 4; ++i)
            z[i] = *(const float4*)(zt + k * 256 + i * 64 + rg * 4);
        float4 ta = *(const float4*)(tt + k * 256 + ng * 8);
        float4 tb = *(const float4*)(tt + k * 256 + ng * 8 + 4);
        float tn[8] = {ta.x, ta.y, ta.z, ta.w, tb.x, tb.y, tb.z, tb.w};
#pragma unroll
        for (int i = 0; i < 4; ++i)
#pragma unroll
            for (int n = 0; n < 8; ++n) {
                acc[i][0][n] = fmaf(z[i].x, tn[n], acc[i][0][n]);
                acc[i][1][n] = fmaf(z[i].y, tn[n], acc[i][1][n]);
                acc[i][2][n] = fmaf(z[i].z, tn[n], acc[i][2][n]);
                acc[i][3][n] = fmaf(z[i].w, tn[n], acc[i][3][n]);
            }
    }
    // store: out[b0+i][n0 + ng*8 + n][rg*4 .. +3] -- coalesced float4
#pragma unroll
    for (int i = 0; i < 4; ++i) {
        float* op = out + ((size_t)(b0 + i) * NFFT + n0 + ng * 8) * CC + rg * 4;
#pragma unroll
        for (int n = 0; n < 8; ++n)
            *(float4*)(op + (size_t)n * CC) =
                make_float4(acc[i][0][n], acc[i][1][n], acc[i][2][n], acc[i][3][n]);
    }
}

extern "C" void kernel_launch(void* const* d_in, const int* in_sizes, int n_in,
                              void* d_out, int out_size, void* d_ws, size_t ws_size,
                              hipStream_t stream) {
    const float* f   = (const float*)d_in[0];
    const float* p   = (const float*)d_in[1];
    const float* W1r = (const float*)d_in[2];
    const float* b1r = (const float*)d_in[3];
    const float* W2r = (const float*)d_in[4];
    const float* b2r = (const float*)d_in[5];
    const float* W1c = (const float*)d_in[6];
    const float* b1c = (const float*)d_in[7];
    const float* W2c = (const float*)d_in[8];
    const float* b2c = (const float*)d_in[9];
    float* ws  = (float*)d_ws;
    float* T   = ws + OFF_T;
    float* Hp  = ws + OFF_H;
    float* X   = ws + OFF_X;
    float* Yw  = ws + OFF_Y;
    float* P   = ws + OFF_P;
    float* Kc  = ws + OFF_K;     // aliases P (dead ranges, stream-ordered)
    float* o   = (float*)d_out;

    hipFuncSetAttribute(reinterpret_cast<const void*>(&k_idft2),
                        hipFuncAttributeMaxDynamicSharedMemorySize, 131072);

    k_twiddle<<<(NFFT * KMAX) / 256, 256, 0, stream>>>(T);
    k_h      <<<1, 320, 0, stream>>>(p, W1r, b1r, W1c, b1c, Hp);
    k_dft2   <<<dim3(NCH, 4), 512, 0, stream>>>(f, T, P);
    k_reduce2<<<dim3(BB, 16), 256, 0, stream>>>(P, X);
    k_kb     <<<KD / 256, 256, 0, stream>>>(W2r, b2r, W2c, b2c, Hp, Kc);
    k_mix    <<<dim3(KMAX, BB), 256, 0, stream>>>(Kc, X, Yw);
    k_idft2  <<<dim3(NFFT / 256, 8), 512, 131072, stream>>>(Yw, T, o);
}

// Round 5
// 219.235 us; speedup vs baseline: 1.9425x; 1.1064x over previous
//
#include <hip/hip_runtime.h>
#include <math.h>

#define NFFT 8192
#define KMAX 32
#define BB   32
#define CC   64
#define HH   10
#define KD   (KMAX*CC*CC)   // 131072

// ---- workspace float offsets ----
#define OFF_T   0
#define SZ_T    (NFFT*KMAX*2)           // 524288 (2 MiB twiddle: cos,sin of +2pi*n*k/N)
#define OFF_H   (OFF_T + SZ_T)
#define SZ_H    768
#define OFF_X   (OFF_H + SZ_H)
#define SZ_X    (BB*KMAX*CC*2)          // 131072  X[b][j][c][2]
#define OFF_Y   (OFF_X + SZ_X)
#define SZ_Y    (BB*CC*KMAX*2)          // 131072  Y[b][o][k][2]
#define NCH     64
#define CHUNK   (NFFT/NCH)              // 128
// P[ch][b][comp][c] (33.5 MB) aliases Kc[b][k][i][o][2] (33.5 MB):
// P is dead after k_reduce2; Kc is written by k_kb afterwards (stream-ordered).
#define OFF_P   (OFF_Y + SZ_Y)
#define SZ_P    (NCH*BB*64*CC)          // 8388608
#define OFF_K   OFF_P

// iDFT LDS padding: k-stride 132 floats (mult of 4 -> aligned b128; 132%32=4 -> banks rotate)
#define PAD 132

// twiddle table: T[n][2j]=cos(2pi*n*j/N), T[n][2j+1]=sin(2pi*n*j/N)
__global__ __launch_bounds__(256) void k_twiddle(float* __restrict__ T) {
    int id = blockIdx.x * 256 + threadIdx.x;      // 0 .. N*KMAX-1
    int n = id >> 5, k = id & 31;
    int t = (n * k) & (NFFT - 1);                 // exact integer phase
    float s, c;
    sincospif(2.0f * (float)t / (float)NFFT, &s, &c);
    ((float2*)T)[id] = make_float2(c, s);
}

__global__ void k_h(const float* __restrict__ p,
                    const float* __restrict__ W1r, const float* __restrict__ b1r,
                    const float* __restrict__ W1c, const float* __restrict__ b1c,
                    float* __restrict__ Hws) {
    int t = threadIdx.x;
    if (t < BB * HH) {
        int b = t / HH, j = t % HH;
        float xr = p[b] * W1r[j] + b1r[j];
        float xc = p[b] * W1c[j] + b1c[j];
        Hws[t]            = xr / (1.0f + expf(-xr));
        Hws[BB * HH + t]  = xc / (1.0f + expf(-xc));
    }
}

// Stage A: truncated DFT. Block=(ch, bg): 4 b, 128 n. Wave w owns modes w*4..w*4+3.
// 32 acc/thread; grid 512 blocks -> 2 blocks/CU -> 4 waves/SIMD (was 2).
__global__ __launch_bounds__(512, 4) void k_dft3(const float* __restrict__ f,
                                                 const float* __restrict__ T,
                                                 float* __restrict__ P) {
    __shared__ float Ts[CHUNK * 64];              // 32 KB T strip
    const int ch = blockIdx.x;
    const int b0 = blockIdx.y * 4;
    const int t  = threadIdx.x;
    {   // stage T strip: 8192 floats, coalesced float4
        const float4* src = (const float4*)(T + (size_t)ch * CHUNK * 64);
        float4* dst = (float4*)Ts;
#pragma unroll
        for (int q = 0; q < 4; ++q) dst[t + q * 512] = src[t + q * 512];
    }
    __syncthreads();
    const int c = t & 63;
    const int w = t >> 6;                         // wave id: modes j0 = w*4
    float accR[4][4], accI[4][4];
#pragma unroll
    for (int bi = 0; bi < 4; ++bi)
#pragma unroll
        for (int m = 0; m < 4; ++m) { accR[bi][m] = 0.f; accI[bi][m] = 0.f; }
    const float* fp = f + ((size_t)b0 * NFFT + ch * CHUNK) * CC + c;
#pragma unroll 4
    for (int n = 0; n < CHUNK; ++n) {
        float fv[4];
#pragma unroll
        for (int bi = 0; bi < 4; ++bi)
            fv[bi] = fp[(size_t)bi * NFFT * CC + n * CC];   // coalesced
        float4 t0 = *(const float4*)(Ts + n * 64 + w * 8);   // uniform broadcast
        float4 t1 = *(const float4*)(Ts + n * 64 + w * 8 + 4);
#pragma unroll
        for (int bi = 0; bi < 4; ++bi) {
            accR[bi][0] = fmaf(fv[bi],  t0.x, accR[bi][0]);
            accI[bi][0] = fmaf(-fv[bi], t0.y, accI[bi][0]);
            accR[bi][1] = fmaf(fv[bi],  t0.z, accR[bi][1]);
            accI[bi][1] = fmaf(-fv[bi], t0.w, accI[bi][1]);
            accR[bi][2] = fmaf(fv[bi],  t1.x, accR[bi][2]);
            accI[bi][2] = fmaf(-fv[bi], t1.y, accI[bi][2]);
            accR[bi][3] = fmaf(fv[bi],  t1.z, accR[bi][3]);
            accI[bi][3] = fmaf(-fv[bi], t1.w, accI[bi][3]);
        }
    }
    // P[ch][b][comp][c], comp = w*8 + 2m (+1 for imag) -- coalesced dword stores
#pragma unroll
    for (int bi = 0; bi < 4; ++bi) {
        float* Pp = P + (((size_t)ch * BB + b0 + bi) * 64 + w * 8) * CC + c;
#pragma unroll
        for (int m = 0; m < 4; ++m) {
            Pp[(2 * m) * CC]     = accR[bi][m];
            Pp[(2 * m + 1) * CC] = accI[bi][m];
        }
    }
}

// reduce partials over 64 chunks -> X[b][j][c][2]
__global__ __launch_bounds__(256) void k_reduce2(const float* __restrict__ P,
                                                 float* __restrict__ X) {
    int t = threadIdx.x;
    int c = t & 63, d = t >> 6;
    int b = blockIdx.x, cg = blockIdx.y;          // cg 0..15
    int comp = cg * 4 + d;
    const float* Pp = P + ((size_t)b * 64 + comp) * CC + c;
    float acc = 0.f;
#pragma unroll 8
    for (int ch = 0; ch < NCH; ++ch)
        acc += Pp[(size_t)ch * BB * 64 * CC];     // coalesced
    int j = comp >> 1, ri = comp & 1;
    X[(((size_t)b * KMAX + j) * CC + c) * 2 + ri] = acc;
}

// Stage B: complex kernel Kc[b][k][i][o][2]; W2 read once for all 32 b.
__global__ __launch_bounds__(256) void k_kb(const float* __restrict__ W2r, const float* __restrict__ b2r,
                                            const float* __restrict__ W2c, const float* __restrict__ b2c,
                                            const float* __restrict__ Hws, float* __restrict__ Kc) {
    __shared__ float h[640];
    int tid = threadIdx.x;
    h[tid] = Hws[tid];
    h[256 + tid] = Hws[256 + tid];
    if (tid < 128) h[512 + tid] = Hws[512 + tid];
    __syncthreads();
    int idx = blockIdx.x * 256 + tid;
    float wr[HH], wc[HH];
#pragma unroll
    for (int j = 0; j < HH; ++j) {
        wr[j] = W2r[(size_t)j * KD + idx];
        wc[j] = W2c[(size_t)j * KD + idx];
    }
    float br = b2r[idx], bc = b2c[idx];
    float2* outp = (float2*)Kc + idx;
    for (int b = 0; b < BB; ++b) {
        float rk = br, ck = bc;
#pragma unroll
        for (int j = 0; j < HH; ++j) {
            rk = fmaf(h[b * HH + j],       wr[j], rk);
            ck = fmaf(h[320 + b * HH + j], wc[j], ck);
        }
        outp[(size_t)b * KD] = make_float2(rk, ck);
    }
}

// Stage C: y[b,o,k] = sum_i Kc[b,k,i,o] * X[b,i,k] (complex), scaled 1/N
__global__ __launch_bounds__(256) void k_mix(const float* __restrict__ Kc,
                                             const float* __restrict__ X,
                                             float* __restrict__ Y) {
    int k = blockIdx.x, b = blockIdx.y;
    int o = threadIdx.x & 63, ig = threadIdx.x >> 6;
    __shared__ float xs[128];
    __shared__ float red[4][64][2];
    if (threadIdx.x < 32)
        ((float4*)xs)[threadIdx.x] =
            ((const float4*)(X + ((size_t)(b * KMAX + k) * CC) * 2))[threadIdx.x];
    __syncthreads();
    const float2* Kp = (const float2*)Kc + (size_t)b * KD + k * CC * CC + o;
    float yr = 0.f, yi = 0.f;
#pragma unroll 4
    for (int t = 0; t < 16; ++t) {
        int i = ig * 16 + t;
        float2 rc = Kp[(size_t)i * CC];
        float xr = xs[2 * i], xi = xs[2 * i + 1];
        yr = fmaf(rc.x, xr, yr); yr = fmaf(-rc.y, xi, yr);
        yi = fmaf(rc.x, xi, yi); yi = fmaf(rc.y, xr, yi);
    }
    red[ig][o][0] = yr; red[ig][o][1] = yi;
    __syncthreads();
    if (threadIdx.x < 64) {
        float sr = red[0][o][0] + red[1][o][0] + red[2][o][0] + red[3][o][0];
        float si = red[0][o][1] + red[1][o][1] + red[2][o][1] + red[3][o][1];
        const float sc = 1.0f / (float)NFFT;
        ((float2*)Y)[((size_t)b * CC + o) * KMAX + k] = make_float2(sr * sc, si * sc);
    }
}

// Stage D: iDFT GEMM, M128(2b x 64c) x N128 tile, K=64 comps, padded LDS.
// zt[k][row]: 2j->yr, 2j+1->-yi ; tt[k][nl]: 2j->cos, 2j+1->sin.
__global__ __launch_bounds__(512, 4) void k_idft3(const float* __restrict__ Y,
                                                  const float* __restrict__ T,
                                                  float* __restrict__ out) {
    extern __shared__ float lds[];                // zt[64][PAD] | tt[64][PAD] = 66 KB
    float* zt = lds;
    float* tt = lds + 64 * PAD;
    const int t  = threadIdx.x;
    const int n0 = blockIdx.x * 128;
    const int b0 = blockIdx.y * 2;
    {   // stage: row = t&127 (consecutive lanes -> 2-way-free LDS writes), kh = t>>7
        int row = t & 127, kh = t >> 7;           // kh in [0,4): comp quarter
        const float4* src = (const float4*)(Y + ((size_t)(b0 + (row >> 6)) * CC + (row & 63)) * (KMAX * 2) + kh * 16);
        const float4* ts  = (const float4*)(T + (size_t)(n0 + row) * (KMAX * 2) + kh * 16);
#pragma unroll
        for (int q = 0; q < 4; ++q) {
            float4 v = src[q];
            int k = kh * 16 + q * 4;
            zt[(k + 0) * PAD + row] =  v.x;
            zt[(k + 1) * PAD + row] = -v.y;       // -yi
            zt[(k + 2) * PAD + row] =  v.z;
            zt[(k + 3) * PAD + row] = -v.w;
            float4 u = ts[q];
            tt[(k + 0) * PAD + row] = u.x;
            tt[(k + 1) * PAD + row] = u.y;
            tt[(k + 2) * PAD + row] = u.z;
            tt[(k + 3) * PAD + row] = u.w;
        }
    }
    __syncthreads();
    const int rg = t & 31;                        // rows rg*4..rg*4+3 (bank-balanced b128)
    const int ng = t >> 5;                        // n cols ng*8..ng*8+7
    float acc[4][8];
#pragma unroll
    for (int r = 0; r < 4; ++r)
#pragma unroll
        for (int n = 0; n < 8; ++n) acc[r][n] = 0.f;
#pragma unroll 2
    for (int k = 0; k < 64; ++k) {
        float4 z  = *(const float4*)(zt + k * PAD + rg * 4);
        float4 ta = *(const float4*)(tt + k * PAD + ng * 8);
        float4 tb = *(const float4*)(tt + k * PAD + ng * 8 + 4);
        float tn[8] = {ta.x, ta.y, ta.z, ta.w, tb.x, tb.y, tb.z, tb.w};
#pragma unroll
        for (int n = 0; n < 8; ++n) {
            acc[0][n] = fmaf(z.x, tn[n], acc[0][n]);
            acc[1][n] = fmaf(z.y, tn[n], acc[1][n]);
            acc[2][n] = fmaf(z.z, tn[n], acc[2][n]);
            acc[3][n] = fmaf(z.w, tn[n], acc[3][n]);
        }
    }
    // store: out[b0+(rg>>4)][n0+ng*8+n][(rg&15)*4 .. +3] -- coalesced float4
    float* op = out + ((size_t)(b0 + (rg >> 4)) * NFFT + n0 + ng * 8) * CC + (rg & 15) * 4;
#pragma unroll
    for (int n = 0; n < 8; ++n)
        *(float4*)(op + (size_t)n * CC) =
            make_float4(acc[0][n], acc[1][n], acc[2][n], acc[3][n]);
}

extern "C" void kernel_launch(void* const* d_in, const int* in_sizes, int n_in,
                              void* d_out, int out_size, void* d_ws, size_t ws_size,
                              hipStream_t stream) {
    const float* f   = (const float*)d_in[0];
    const float* p   = (const float*)d_in[1];
    const float* W1r = (const float*)d_in[2];
    const float* b1r = (const float*)d_in[3];
    const float* W2r = (const float*)d_in[4];
    const float* b2r = (const float*)d_in[5];
    const float* W1c = (const float*)d_in[6];
    const float* b1c = (const float*)d_in[7];
    const float* W2c = (const float*)d_in[8];
    const float* b2c = (const float*)d_in[9];
    float* ws  = (float*)d_ws;
    float* T   = ws + OFF_T;
    float* Hp  = ws + OFF_H;
    float* X   = ws + OFF_X;
    float* Yw  = ws + OFF_Y;
    float* P   = ws + OFF_P;
    float* Kc  = ws + OFF_K;     // aliases P (dead ranges, stream-ordered)
    float* o   = (float*)d_out;

    hipFuncSetAttribute(reinterpret_cast<const void*>(&k_idft3),
                        hipFuncAttributeMaxDynamicSharedMemorySize, 2 * 64 * PAD * 4);

    k_twiddle<<<(NFFT * KMAX) / 256, 256, 0, stream>>>(T);
    k_h      <<<1, 320, 0, stream>>>(p, W1r, b1r, W1c, b1c, Hp);
    k_dft3   <<<dim3(NCH, 8), 512, 0, stream>>>(f, T, P);
    k_reduce2<<<dim3(BB, 16), 256, 0, stream>>>(P, X);
    k_kb     <<<KD / 256, 256, 0, stream>>>(W2r, b2r, W2c, b2c, Hp, Kc);
    k_mix    <<<dim3(KMAX, BB), 256, 0, stream>>>(Kc, X, Yw);
    k_idft3  <<<dim3(NFFT / 128, BB / 2), 512, 2 * 64 * PAD * 4, stream>>>(Yw, T, o);
}